// Round 3
// baseline (351.313 us; speedup 1.0000x reference)
//
#include <hip/hip_runtime.h>
#include <cmath>

// ---------------------------------------------------------------------------
// JPEG compress (YCbCr + 2x2 chroma pool + 8x8 DCT + quantize/round).
//
// Numerics contract (VERIFIED r4/r6/r9, absmax 0.0): f32 end-to-end, every
// accumulation step is mul-then-add with TWO roundings (no FMA). All
// value-path mul/add/sub are inline-asm v_mul_f32 / v_add_f32 / v_sub_f32
// (asm boundary blocks FMA formation). fdiv/rint stay as builtins.
//
// Recipe per output (DO NOT CHANGE):
//   t_c   = rn(x_c * 255)
//   y     = chain c=R,G,B: a = rn(a + rn(t_c*k_c));  X = rn(a - 128)
//   cb/cr = same chain + 128; pool ((p00+p01)+p10)+p11 * 0.25; - 128
//   dct_i = 64-step chain j=(x,y) row-major from 0: a = rn(a + rn(T_ij*X_j))
//   outv  = rintf( rn( rn(sc_i * dct_i) / q_i ) )
//
// R9->R10: SAME structure (one 8x8 block per lane, no LDS), fix the X[64]
// scratch demotion r9's counters proved (VGPR_Count=64 can't hold X ->
// spill: WRITE 122MB, FETCH 241MB, VALUBusy 29%, 234us).
//   1. CFor<> template recursion replaces #pragma unroll wherever X is
//      indexed -> indices are literal constants at IR-gen -> SROA promotes
//      X to 64 scalar SSA values BEFORE any unroll pass.
//   2. amdgpu_waves_per_eu(4,4) pins the allocator occupancy target: budget
//      exactly 128 VGPRs, it may not squeeze to 64 by spilling.
//   3. DCT consumes T rows one i at a time (~64 wave-uniform SGPR values
//      live, under the 102 SGPR budget; 4-wide grouping only for the
//      float4 store).
// ---------------------------------------------------------------------------

namespace jc {

constexpr double c1 = 0.98078528040323044912618223613424;  // cos(1*pi/16)
constexpr double c2 = 0.92387953251128675612818318939679;  // cos(2*pi/16)
constexpr double c3 = 0.83146961230254523707878837761791;  // cos(3*pi/16)
constexpr double c4 = 0.70710678118654752440084436210485;  // cos(4*pi/16)
constexpr double c5 = 0.55557023301960222474283081394853;  // cos(5*pi/16)
constexpr double c6 = 0.38268343236508977172845998403040;  // cos(6*pi/16)
constexpr double c7 = 0.19509032201612826784828486847702;  // cos(7*pi/16)
constexpr double alpha0 = 0.70710678118654746171979706919384;  // 1.0/np.sqrt(2)

struct Tab {
  float tr[4096];  // ROW-major: tr[i*64+j] = f32(CX[x][u]*CX[y][v]), i=(u,v), j=(x,y)
  float sc[64];    // f32(f64(alpha_u*alpha_v)*0.25)
  float yq[64];
  float cq[64];
  constexpr Tab() : tr(), sc(), yq(), cq() {
    const double CX[8][8] = {  // CX[x][u] = cos((2x+1)u*pi/16)
      {1.0,  c1,  c2,  c3,  c4,  c5,  c6,  c7},
      {1.0,  c3,  c6, -c7, -c4, -c1, -c2, -c5},
      {1.0,  c5, -c6, -c1, -c4,  c7,  c2,  c3},
      {1.0,  c7, -c2, -c5,  c4,  c3, -c6, -c1},
      {1.0, -c7, -c2,  c5,  c4, -c3, -c6,  c1},
      {1.0, -c5, -c6,  c1, -c4, -c7,  c2, -c3},
      {1.0, -c3,  c6,  c7, -c4,  c1, -c2,  c5},
      {1.0, -c1,  c2, -c3,  c4, -c5,  c6, -c7}};
    for (int i = 0; i < 64; ++i) {
      const int u = i >> 3, v = i & 7;
      for (int j = 0; j < 64; ++j) {
        const int x = j >> 3, y = j & 7;
        tr[i * 64 + j] = (float)(CX[x][u] * CX[y][v]);
      }
      const double au = (u == 0) ? alpha0 : 1.0;
      const double av = (v == 0) ? alpha0 : 1.0;
      sc[i] = (float)((au * av) * 0.25);
    }
    const int YT[64] = {
      16, 11, 10, 16, 24, 40, 51, 61,
      12, 12, 14, 19, 26, 58, 60, 55,
      14, 13, 16, 24, 40, 57, 69, 56,
      14, 17, 22, 29, 51, 87, 80, 62,
      18, 22, 37, 56, 68, 109, 103, 77,
      24, 35, 55, 64, 81, 104, 113, 92,
      49, 64, 78, 87, 103, 121, 120, 101,
      72, 92, 95, 98, 112, 100, 103, 99};
    const int CT[64] = {
      17, 18, 24, 47, 99, 99, 99, 99,
      18, 21, 26, 66, 99, 99, 99, 99,
      24, 26, 56, 99, 99, 99, 99, 99,
      47, 66, 99, 99, 99, 99, 99, 99,
      99, 99, 99, 99, 99, 99, 99, 99,
      99, 99, 99, 99, 99, 99, 99, 99,
      99, 99, 99, 99, 99, 99, 99, 99,
      99, 99, 99, 99, 99, 99, 99, 99};
    for (int i = 0; i < 64; ++i) {
      yq[i] = (float)YT[i];
      cq[i] = (float)CT[i];
    }
  }
};

__device__ constexpr Tab TT;

}  // namespace jc

// ---- compile-time for: every loop index touching X is a literal ----
template <int I> struct IC { static constexpr int v = I; };
template <int N> struct CFor {
  template <typename F> static __device__ __forceinline__ void run(F&& f) {
    CFor<N - 1>::run(f);
    f(IC<N - 1>{});
  }
};
template <> struct CFor<0> {
  template <typename F> static __device__ __forceinline__ void run(F&&) {}
};

template <int K> __device__ __forceinline__ float pick8(const float4& a, const float4& b) {
  if constexpr (K == 0) return a.x;
  else if constexpr (K == 1) return a.y;
  else if constexpr (K == 2) return a.z;
  else if constexpr (K == 3) return a.w;
  else if constexpr (K == 4) return b.x;
  else if constexpr (K == 5) return b.y;
  else if constexpr (K == 6) return b.z;
  else return b.w;
}
template <int K> __device__ __forceinline__ float pick4(const float4& a) {
  if constexpr (K == 0) return a.x;
  else if constexpr (K == 1) return a.y;
  else if constexpr (K == 2) return a.z;
  else return a.w;
}

// ---- contraction-proof f32 ops (asm boundary blocks FMA formation) ----
__device__ __forceinline__ float vmul(float a, float b) {
  float r; asm("v_mul_f32 %0, %1, %2" : "=v"(r) : "v"(a), "v"(b)); return r;
}
// SGPR x VGPR multiply: identical arithmetic, keeps wave-uniform T in SGPRs.
__device__ __forceinline__ float vmulS(float s, float v) {
  float r; asm("v_mul_f32 %0, %1, %2" : "=v"(r) : "s"(s), "v"(v)); return r;
}
__device__ __forceinline__ float vadd(float a, float b) {
  float r; asm("v_add_f32 %0, %1, %2" : "=v"(r) : "v"(a), "v"(b)); return r;
}
__device__ __forceinline__ float vsubf(float a, float b) {  // a - b
  float r; asm("v_sub_f32 %0, %1, %2" : "=v"(r) : "v"(a), "v"(b)); return r;
}

// chroma chain from pre-scaled t values (tR=rn(R*255) etc.), + 128 shift
__device__ __forceinline__ float chro_t(float tR, float tG, float tB,
                                        float kR, float kG, float kB) {
  float a = vmul(tR, kR);
  a = vadd(a, vmul(tG, kG));
  a = vadd(a, vmul(tB, kB));
  return vadd(a, 128.0f);
}

// grid: 768 wg x 256 thr = 3072 waves; wave = 64 blocks of one kind.
// per image (96 waves): wv 0..63 Y (block row wv, col=lane),
//                       wv 64..79 Cb (blocks m*64+lane), wv 80..95 Cr.
__global__ __launch_bounds__(256)
__attribute__((amdgpu_waves_per_eu(4, 4)))
void jpeg_kernel(const float* __restrict__ img, float* __restrict__ out) {
  const int t = threadIdx.x;
  const int lane = t & 63;
  const int w = __builtin_amdgcn_readfirstlane(t >> 6);  // uniform wave id
  const int gw = blockIdx.x * 4 + w;
  const int im = gw / 96;   // image 0..31 (uniform -> scalar div)
  const int wv = gw - im * 96;

  const float* base = img + (size_t)im * 786432;  // 3*512*512
  float X[64];  // SROA-split into 64 scalars (all indices literal via CFor)
  unsigned obase;
  bool isY;

  if (wv < 64) {
    // ---------------- Y wave: lane owns Y block (row wv, col lane) ----------
    isY = true;
    const float* rp = base + (wv * 8) * 512 + lane * 8;
    CFor<8>::run([&](auto icr) {
      constexpr int rr = decltype(icr)::v;
      const float* p0 = rp + rr * 512;
      const float4 r0 = *(const float4*)(p0);
      const float4 r1 = *(const float4*)(p0 + 4);
      const float4 g0 = *(const float4*)(p0 + 262144);
      const float4 g1 = *(const float4*)(p0 + 262144 + 4);
      const float4 b0 = *(const float4*)(p0 + 524288);
      const float4 b1 = *(const float4*)(p0 + 524288 + 4);
      CFor<8>::run([&](auto icy) {
        constexpr int y = decltype(icy)::v;
        const float tR = vmul(pick8<y>(r0, r1), 255.0f);
        const float tG = vmul(pick8<y>(g0, g1), 255.0f);
        const float tB = vmul(pick8<y>(b0, b1), 255.0f);
        float a = vmul(tR, 0.299f);
        a = vadd(a, vmul(tG, 0.587f));
        a = vadd(a, vmul(tB, 0.114f));
        X[rr * 8 + y] = vsubf(a, 128.0f);
      });
    });
    obase = ((unsigned)(im * 4096 + wv * 64 + lane)) << 6;
  } else {
    // ------------- chroma wave: lane owns one Cb or Cr block ---------------
    isY = false;
    const int cwv = wv - 64;
    const bool isCb = (cwv < 16);
    const int m = cwv & 15;
    const int cy = 2 * m + (lane >> 5);  // chroma block row 0..31
    const int cx = lane & 31;            // chroma block col 0..31
    const float kR = isCb ? -0.168736f : 0.5f;
    const float kG = isCb ? -0.331264f : -0.418688f;
    const float kB = isCb ? 0.5f : -0.081312f;
    const float* rp = base + (cy * 16) * 512 + cx * 16;
    CFor<8>::run([&](auto icq) {   // pooled row q <- pixel rows 2q, 2q+1
      constexpr int q = decltype(icq)::v;
      CFor<4>::run([&](auto ich) { // pooled col pair h: pixel cols 4h..4h+3
        constexpr int h = decltype(ich)::v;
        const float* p0 = rp + (2 * q) * 512 + 4 * h;
        const float4 r0 = *(const float4*)(p0);
        const float4 r1 = *(const float4*)(p0 + 512);
        const float4 g0 = *(const float4*)(p0 + 262144);
        const float4 g1 = *(const float4*)(p0 + 262144 + 512);
        const float4 b0 = *(const float4*)(p0 + 524288);
        const float4 b1 = *(const float4*)(p0 + 524288 + 512);
        CFor<2>::run([&](auto icc) {  // pooled col = 2h + c2
          constexpr int c2 = decltype(icc)::v;
          constexpr int e = 2 * c2, o = e + 1;
          const float p00 = chro_t(vmul(pick4<e>(r0), 255.0f),
                                   vmul(pick4<e>(g0), 255.0f),
                                   vmul(pick4<e>(b0), 255.0f), kR, kG, kB);
          const float p01 = chro_t(vmul(pick4<o>(r0), 255.0f),
                                   vmul(pick4<o>(g0), 255.0f),
                                   vmul(pick4<o>(b0), 255.0f), kR, kG, kB);
          const float p10 = chro_t(vmul(pick4<e>(r1), 255.0f),
                                   vmul(pick4<e>(g1), 255.0f),
                                   vmul(pick4<e>(b1), 255.0f), kR, kG, kB);
          const float p11 = chro_t(vmul(pick4<o>(r1), 255.0f),
                                   vmul(pick4<o>(g1), 255.0f),
                                   vmul(pick4<o>(b1), 255.0f), kR, kG, kB);
          const float s = vadd(vadd(vadd(p00, p01), p10), p11);
          X[q * 8 + 2 * h + c2] = vsubf(vmul(s, 0.25f), 128.0f);
        });
      });
    });
    obase = 8388608u + (isCb ? 0u : 2097152u) +
            (((unsigned)(im * 1024 + m * 64 + lane)) << 6);
  }

  // ---------------- DCT + quantize: i wave-uniform, T row in SGPRs ---------
  const float* __restrict__ qt = isY ? jc::TT.yq : jc::TT.cq;  // uniform select
  float* op = out + obase;
#pragma unroll 1
  for (int i0 = 0; i0 < 64; i0 += 4) {
    float4 v4;
    CFor<4>::run([&](auto icii) {
      constexpr int ii = decltype(icii)::v;
      const int i = i0 + ii;
      const float* __restrict__ trow = jc::TT.tr + i * 64;  // uniform -> s_load
      float acc = 0.0f;
      CFor<64>::run([&](auto icj) {
        constexpr int j = decltype(icj)::v;
        acc = vadd(acc, vmulS(trow[j], X[j]));  // rn(acc + rn(T*X)), row-major j
      });
      const float o = rintf(__fdiv_rn(vmulS(jc::TT.sc[i], acc), qt[i]));
      if constexpr (ii == 0) v4.x = o;
      else if constexpr (ii == 1) v4.y = o;
      else if constexpr (ii == 2) v4.z = o;
      else v4.w = o;
    });
    *(float4*)(op + i0) = v4;  // lane-local 16B
  }
}

extern "C" void kernel_launch(void* const* d_in, const int* in_sizes, int n_in,
                              void* d_out, int out_size, void* d_ws, size_t ws_size,
                              hipStream_t stream) {
  (void)in_sizes; (void)n_in; (void)d_ws; (void)ws_size; (void)out_size;
  const float* img = (const float*)d_in[0];
  float* out = (float*)d_out;
  jpeg_kernel<<<dim3(768), dim3(256), 0, stream>>>(img, out);
}

// Round 4
// 320.421 us; speedup vs baseline: 1.0964x; 1.0964x over previous
//
#include <hip/hip_runtime.h>
#include <cmath>

// ---------------------------------------------------------------------------
// JPEG compress (YCbCr + 2x2 chroma pool + 8x8 DCT + quantize/round).
//
// Numerics contract (VERIFIED r4/r6/r9/r10, absmax 0.0): f32 end-to-end,
// every accumulation step is mul-then-add with TWO roundings (no FMA). All
// value-path mul/add/sub are inline-asm v_mul_f32 / v_add_f32 / v_sub_f32
// (asm boundary blocks FMA formation). fdiv/rint stay as builtins.
//
// Recipe per output (DO NOT CHANGE):
//   t_c   = rn(x_c * 255)
//   y     = chain c=R,G,B: a = rn(a + rn(t_c*k_c));  X = rn(a - 128)
//   cb/cr = same chain + 128; pool ((p00+p01)+p10)+p11 * 0.25; - 128
//   dct_i = 64-step chain j=(x,y) row-major from 0: a = rn(a + rn(T_ij*X_j))
//   outv  = rintf( rn( rn(sc_i * dct_i) / q_i ) )
//
// R10->R11 (same block-per-lane dataflow, three fixes):
//  A. STORES were the hidden cost: 16B pieces at 256B stride -> write-
//     allocate FETCH (+50MB), partial-line evictions (WRITE 132MB vs 50),
//     L2/L3 churn killing chroma L3 hits (FETCH fit: 96+96+50=242~=241
//     measured). Fix: transpose 16-coeff slabs through wave-private LDS
//     (64 blocks x stride 20 floats); stores become full-64B-line
//     global_store_dwordx4. No barriers (wave-private, DS in-order).
//  B. X[64] -> struct of 64 NAMED floats (if-constexpr getters): no array
//     exists, SROA cannot fail to promote.
//  C. asm clobber of v64..v127 at entry: vgpr_count >= 128, making the
//     8-wave/64-VGPR occupancy target unreachable -> allocator stops
//     spilling to chase it. Plus amdgpu_waves_per_eu(2,4).
// ---------------------------------------------------------------------------

namespace jc {

constexpr double c1 = 0.98078528040323044912618223613424;  // cos(1*pi/16)
constexpr double c2 = 0.92387953251128675612818318939679;  // cos(2*pi/16)
constexpr double c3 = 0.83146961230254523707878837761791;  // cos(3*pi/16)
constexpr double c4 = 0.70710678118654752440084436210485;  // cos(4*pi/16)
constexpr double c5 = 0.55557023301960222474283081394853;  // cos(5*pi/16)
constexpr double c6 = 0.38268343236508977172845998403040;  // cos(6*pi/16)
constexpr double c7 = 0.19509032201612826784828486847702;  // cos(7*pi/16)
constexpr double alpha0 = 0.70710678118654746171979706919384;  // 1.0/np.sqrt(2)

struct Tab {
  float tr[4096];  // ROW-major: tr[i*64+j] = f32(CX[x][u]*CX[y][v]), i=(u,v), j=(x,y)
  float sc[64];    // f32(f64(alpha_u*alpha_v)*0.25)
  float yq[64];
  float cq[64];
  constexpr Tab() : tr(), sc(), yq(), cq() {
    const double CX[8][8] = {  // CX[x][u] = cos((2x+1)u*pi/16)
      {1.0,  c1,  c2,  c3,  c4,  c5,  c6,  c7},
      {1.0,  c3,  c6, -c7, -c4, -c1, -c2, -c5},
      {1.0,  c5, -c6, -c1, -c4,  c7,  c2,  c3},
      {1.0,  c7, -c2, -c5,  c4,  c3, -c6, -c1},
      {1.0, -c7, -c2,  c5,  c4, -c3, -c6,  c1},
      {1.0, -c5, -c6,  c1, -c4, -c7,  c2, -c3},
      {1.0, -c3,  c6,  c7, -c4,  c1, -c2,  c5},
      {1.0, -c1,  c2, -c3,  c4, -c5,  c6, -c7}};
    for (int i = 0; i < 64; ++i) {
      const int u = i >> 3, v = i & 7;
      for (int j = 0; j < 64; ++j) {
        const int x = j >> 3, y = j & 7;
        tr[i * 64 + j] = (float)(CX[x][u] * CX[y][v]);
      }
      const double au = (u == 0) ? alpha0 : 1.0;
      const double av = (v == 0) ? alpha0 : 1.0;
      sc[i] = (float)((au * av) * 0.25);
    }
    const int YT[64] = {
      16, 11, 10, 16, 24, 40, 51, 61,
      12, 12, 14, 19, 26, 58, 60, 55,
      14, 13, 16, 24, 40, 57, 69, 56,
      14, 17, 22, 29, 51, 87, 80, 62,
      18, 22, 37, 56, 68, 109, 103, 77,
      24, 35, 55, 64, 81, 104, 113, 92,
      49, 64, 78, 87, 103, 121, 120, 101,
      72, 92, 95, 98, 112, 100, 103, 99};
    const int CT[64] = {
      17, 18, 24, 47, 99, 99, 99, 99,
      18, 21, 26, 66, 99, 99, 99, 99,
      24, 26, 56, 99, 99, 99, 99, 99,
      47, 66, 99, 99, 99, 99, 99, 99,
      99, 99, 99, 99, 99, 99, 99, 99,
      99, 99, 99, 99, 99, 99, 99, 99,
      99, 99, 99, 99, 99, 99, 99, 99,
      99, 99, 99, 99, 99, 99, 99, 99};
    for (int i = 0; i < 64; ++i) {
      yq[i] = (float)YT[i];
      cq[i] = (float)CT[i];
    }
  }
};

__device__ constexpr Tab TT;

}  // namespace jc

// ---- compile-time for ----
template <int I> struct IC { static constexpr int v = I; };
template <int N> struct CFor {
  template <typename F> static __device__ __forceinline__ void run(F&& f) {
    CFor<N - 1>::run(f);
    f(IC<N - 1>{});
  }
};
template <> struct CFor<0> {
  template <typename F> static __device__ __forceinline__ void run(F&&) {}
};

// ---- 64 NAMED floats (no array anywhere -> guaranteed SSA scalars) ----
struct O8 {
  float a0, a1, a2, a3, a4, a5, a6, a7;
  template <int K> __device__ __forceinline__ float& at() {
    if constexpr (K == 0) return a0;
    else if constexpr (K == 1) return a1;
    else if constexpr (K == 2) return a2;
    else if constexpr (K == 3) return a3;
    else if constexpr (K == 4) return a4;
    else if constexpr (K == 5) return a5;
    else if constexpr (K == 6) return a6;
    else return a7;
  }
};
struct X64 {
  O8 r0, r1, r2, r3, r4, r5, r6, r7;
  template <int J> __device__ __forceinline__ float& at() {
    if constexpr (J < 8) return r0.template at<J>();
    else if constexpr (J < 16) return r1.template at<J - 8>();
    else if constexpr (J < 24) return r2.template at<J - 16>();
    else if constexpr (J < 32) return r3.template at<J - 24>();
    else if constexpr (J < 40) return r4.template at<J - 32>();
    else if constexpr (J < 48) return r5.template at<J - 40>();
    else if constexpr (J < 56) return r6.template at<J - 48>();
    else return r7.template at<J - 56>();
  }
};

template <int K> __device__ __forceinline__ float pick8(const float4& a, const float4& b) {
  if constexpr (K == 0) return a.x;
  else if constexpr (K == 1) return a.y;
  else if constexpr (K == 2) return a.z;
  else if constexpr (K == 3) return a.w;
  else if constexpr (K == 4) return b.x;
  else if constexpr (K == 5) return b.y;
  else if constexpr (K == 6) return b.z;
  else return b.w;
}
template <int K> __device__ __forceinline__ float pick4(const float4& a) {
  if constexpr (K == 0) return a.x;
  else if constexpr (K == 1) return a.y;
  else if constexpr (K == 2) return a.z;
  else return a.w;
}

// ---- contraction-proof f32 ops (asm boundary blocks FMA formation) ----
__device__ __forceinline__ float vmul(float a, float b) {
  float r; asm("v_mul_f32 %0, %1, %2" : "=v"(r) : "v"(a), "v"(b)); return r;
}
// SGPR x VGPR multiply: identical arithmetic, wave-uniform operand in SGPR.
__device__ __forceinline__ float vmulS(float s, float v) {
  float r; asm("v_mul_f32 %0, %1, %2" : "=v"(r) : "s"(s), "v"(v)); return r;
}
__device__ __forceinline__ float vadd(float a, float b) {
  float r; asm("v_add_f32 %0, %1, %2" : "=v"(r) : "v"(a), "v"(b)); return r;
}
__device__ __forceinline__ float vsubf(float a, float b) {  // a - b
  float r; asm("v_sub_f32 %0, %1, %2" : "=v"(r) : "v"(a), "v"(b)); return r;
}

__device__ __forceinline__ float chro_t(float tR, float tG, float tB,
                                        float kR, float kG, float kB) {
  float a = vmul(tR, kR);
  a = vadd(a, vmul(tG, kG));
  a = vadd(a, vmul(tB, kB));
  return vadd(a, 128.0f);
}

// grid: 768 wg x 256 thr = 3072 waves; wave = 64 blocks of one kind.
// per image (96 waves): wv 0..63 Y (block row wv, col=lane),
//                       wv 64..79 Cb (blocks m*64+lane), wv 80..95 Cr.
__global__ __launch_bounds__(256)
__attribute__((amdgpu_waves_per_eu(2, 4)))
void jpeg_kernel(const float* __restrict__ img, float* __restrict__ out) {
  // Force vgpr_count >= 128: the 8-wave/64-VGPR occupancy target becomes
  // unreachable, so the pressure-driven scheduler stops spilling to chase it.
  asm volatile("" :::
    "v64","v65","v66","v67","v68","v69","v70","v71",
    "v72","v73","v74","v75","v76","v77","v78","v79",
    "v80","v81","v82","v83","v84","v85","v86","v87",
    "v88","v89","v90","v91","v92","v93","v94","v95",
    "v96","v97","v98","v99","v100","v101","v102","v103",
    "v104","v105","v106","v107","v108","v109","v110","v111",
    "v112","v113","v114","v115","v116","v117","v118","v119",
    "v120","v121","v122","v123","v124","v125","v126","v127");

  __shared__ float S[4][64][20];  // per-wave transpose slab: 64 blocks x 16 coeffs, pad 20

  const int t = threadIdx.x;
  const int lane = t & 63;
  const int w = __builtin_amdgcn_readfirstlane(t >> 6);  // uniform wave id
  const int gw = blockIdx.x * 4 + w;
  const int im = gw / 96;   // image 0..31 (uniform -> scalar div)
  const int wv = gw - im * 96;

  const float* base = img + (size_t)im * 786432;  // 3*512*512
  X64 X;          // 64 named scalars, lane's block (row-major j=(x,y))
  unsigned wbase; // wave-level output base (wave's 64 blocks are contiguous)
  bool isY;

  if (wv < 64) {
    // ---------------- Y wave: lane owns Y block (row wv, col lane) ----------
    isY = true;
    const float* rp = base + (wv * 8) * 512 + lane * 8;
    CFor<8>::run([&](auto icr) {
      constexpr int rr = decltype(icr)::v;
      const float* p0 = rp + rr * 512;
      const float4 r0 = *(const float4*)(p0);
      const float4 r1 = *(const float4*)(p0 + 4);
      const float4 g0 = *(const float4*)(p0 + 262144);
      const float4 g1 = *(const float4*)(p0 + 262144 + 4);
      const float4 b0 = *(const float4*)(p0 + 524288);
      const float4 b1 = *(const float4*)(p0 + 524288 + 4);
      CFor<8>::run([&](auto icy) {
        constexpr int y = decltype(icy)::v;
        const float tR = vmul(pick8<y>(r0, r1), 255.0f);
        const float tG = vmul(pick8<y>(g0, g1), 255.0f);
        const float tB = vmul(pick8<y>(b0, b1), 255.0f);
        float a = vmul(tR, 0.299f);
        a = vadd(a, vmul(tG, 0.587f));
        a = vadd(a, vmul(tB, 0.114f));
        X.template at<rr * 8 + y>() = vsubf(a, 128.0f);
      });
    });
    wbase = (unsigned)(im * 262144 + wv * 4096);
  } else {
    // ------------- chroma wave: lane owns one Cb or Cr block ---------------
    isY = false;
    const int cwv = wv - 64;
    const bool isCb = (cwv < 16);
    const int m = cwv & 15;
    const int cy = 2 * m + (lane >> 5);  // chroma block row 0..31
    const int cx = lane & 31;            // chroma block col 0..31
    const float kR = isCb ? -0.168736f : 0.5f;
    const float kG = isCb ? -0.331264f : -0.418688f;
    const float kB = isCb ? 0.5f : -0.081312f;
    const float* rp = base + (cy * 16) * 512 + cx * 16;
    CFor<8>::run([&](auto icq) {   // pooled row q <- pixel rows 2q, 2q+1
      constexpr int q = decltype(icq)::v;
      CFor<4>::run([&](auto ich) { // pooled col pair h: pixel cols 4h..4h+3
        constexpr int h = decltype(ich)::v;
        const float* p0 = rp + (2 * q) * 512 + 4 * h;
        const float4 r0 = *(const float4*)(p0);
        const float4 r1 = *(const float4*)(p0 + 512);
        const float4 g0 = *(const float4*)(p0 + 262144);
        const float4 g1 = *(const float4*)(p0 + 262144 + 512);
        const float4 b0 = *(const float4*)(p0 + 524288);
        const float4 b1 = *(const float4*)(p0 + 524288 + 512);
        CFor<2>::run([&](auto icc) {  // pooled col = 2h + c2
          constexpr int c2 = decltype(icc)::v;
          constexpr int e = 2 * c2, o = e + 1;
          const float p00 = chro_t(vmul(pick4<e>(r0), 255.0f),
                                   vmul(pick4<e>(g0), 255.0f),
                                   vmul(pick4<e>(b0), 255.0f), kR, kG, kB);
          const float p01 = chro_t(vmul(pick4<o>(r0), 255.0f),
                                   vmul(pick4<o>(g0), 255.0f),
                                   vmul(pick4<o>(b0), 255.0f), kR, kG, kB);
          const float p10 = chro_t(vmul(pick4<e>(r1), 255.0f),
                                   vmul(pick4<e>(g1), 255.0f),
                                   vmul(pick4<e>(b1), 255.0f), kR, kG, kB);
          const float p11 = chro_t(vmul(pick4<o>(r1), 255.0f),
                                   vmul(pick4<o>(g1), 255.0f),
                                   vmul(pick4<o>(b1), 255.0f), kR, kG, kB);
          const float s = vadd(vadd(vadd(p00, p01), p10), p11);
          X.template at<q * 8 + 2 * h + c2>() = vsubf(vmul(s, 0.25f), 128.0f);
        });
      });
    });
    wbase = 8388608u + (isCb ? 0u : 2097152u) + (unsigned)(im * 65536 + m * 4096);
  }

  // ------------- DCT + quantize + LDS-transposed coalesced store ----------
  const float* __restrict__ qt = isY ? jc::TT.yq : jc::TT.cq;  // uniform
  float* wout = out + wbase;

#pragma unroll 1
  for (int f = 0; f < 4; ++f) {          // slab: coeffs f*16 .. f*16+15
#pragma unroll 1
    for (int g = 0; g < 4; ++g) {        // quad of outputs within slab
      float4 v4;
      CFor<4>::run([&](auto icii) {      // 4 independent chains (ILP)
        constexpr int ii = decltype(icii)::v;
        const int i = f * 16 + g * 4 + ii;
        const float* __restrict__ trow = jc::TT.tr + i * 64;  // uniform s_load
        float acc = 0.0f;
        CFor<64>::run([&](auto icj) {
          constexpr int j = decltype(icj)::v;
          acc = vadd(acc, vmulS(trow[j], X.template at<j>()));  // rn chain
        });
        const float o = rintf(__fdiv_rn(vmulS(jc::TT.sc[i], acc), qt[i]));
        if constexpr (ii == 0) v4.x = o;
        else if constexpr (ii == 1) v4.y = o;
        else if constexpr (ii == 2) v4.z = o;
        else v4.w = o;
      });
      *(float4*)&S[w][lane][g * 4] = v4;  // ds_write_b128, wave-private
    }
    // transposed read + full-line stores (DS ops in-order within wave;
    // compiler inserts lgkmcnt waits; no barrier needed -- wave-private slab)
#pragma unroll
    for (int k = 0; k < 4; ++k) {
      const int B = k * 16 + (lane >> 2);       // block within wave
      const int e0 = (lane & 3) * 4;            // coeff quad within slab
      const float4 vv = *(const float4*)&S[w][B][e0];
      *(float4*)&wout[B * 64 + f * 16 + e0] = vv;  // 64B-line-complete stores
    }
  }
}

extern "C" void kernel_launch(void* const* d_in, const int* in_sizes, int n_in,
                              void* d_out, int out_size, void* d_ws, size_t ws_size,
                              hipStream_t stream) {
  (void)in_sizes; (void)n_in; (void)d_ws; (void)ws_size; (void)out_size;
  const float* img = (const float*)d_in[0];
  float* out = (float*)d_out;
  jpeg_kernel<<<dim3(768), dim3(256), 0, stream>>>(img, out);
}

// Round 5
// 316.413 us; speedup vs baseline: 1.1103x; 1.0127x over previous
//
#include <hip/hip_runtime.h>
#include <cmath>

// ---------------------------------------------------------------------------
// JPEG compress (YCbCr + 2x2 chroma pool + 8x8 DCT + quantize/round).
//
// Numerics contract (VERIFIED r4/r6/r9/r10/r11, absmax 0.0): f32 end-to-end,
// every accumulation step is mul-then-add with TWO roundings (no FMA). All
// value-path mul/add/sub are inline-asm v_mul_f32 / v_add_f32 / v_sub_f32
// (asm boundary blocks FMA formation). fdiv/rint stay as builtins.
//
// Recipe per output (DO NOT CHANGE):
//   t_c   = rn(x_c * 255)
//   y     = chain c=R,G,B: a = rn(a + rn(t_c*k_c));  X = rn(a - 128)
//   cb/cr = same chain + 128; pool ((p00+p01)+p10)+p11 * 0.25; - 128
//   dct_i = 64-step chain j=(x,y) row-major from 0: a = rn(a + rn(T_ij*X_j))
//   outv  = rintf( rn( rn(sc_i * dct_i) / q_i ) )
//
// R11->R12: X promotion FINALLY made unconditional. r9-r11 all left X in
// scratch (VGPR 64-72, FETCH 241-348MB, VALUBusy 28%): r9 = rule-#20
// (SROA before unroll); r10/r11 = lambda bodies capturing X by REFERENCE
// plausibly not inlined -> address escape -> alloca stays. This version has
// NO arrays, NO lambdas, NO references in the value path: 64 named locals
// X0..X63, preprocessor-macro straight-line code, helpers strictly by-value.
// DCT = one output at a time (T-row "s"-constrained SGPRs stay ~64 live,
// under budget); 4 outputs buffered -> r11's verified LDS-slab transposed
// full-line stores (WRITE fix confirmed: 132->56MB).
// ---------------------------------------------------------------------------

namespace jc {

constexpr double c1 = 0.98078528040323044912618223613424;
constexpr double c2 = 0.92387953251128675612818318939679;
constexpr double c3 = 0.83146961230254523707878837761791;
constexpr double c4 = 0.70710678118654752440084436210485;
constexpr double c5 = 0.55557023301960222474283081394853;
constexpr double c6 = 0.38268343236508977172845998403040;
constexpr double c7 = 0.19509032201612826784828486847702;
constexpr double alpha0 = 0.70710678118654746171979706919384;  // 1/sqrt(2)

struct Tab {
  float tr[4096];  // ROW-major: tr[i*64+j] = f32(CX[x][u]*CX[y][v]), i=(u,v), j=(x,y)
  float sc[64];    // f32(f64(alpha_u*alpha_v)*0.25)
  float yq[64];
  float cq[64];
  constexpr Tab() : tr(), sc(), yq(), cq() {
    const double CX[8][8] = {
      {1.0,  c1,  c2,  c3,  c4,  c5,  c6,  c7},
      {1.0,  c3,  c6, -c7, -c4, -c1, -c2, -c5},
      {1.0,  c5, -c6, -c1, -c4,  c7,  c2,  c3},
      {1.0,  c7, -c2, -c5,  c4,  c3, -c6, -c1},
      {1.0, -c7, -c2,  c5,  c4, -c3, -c6,  c1},
      {1.0, -c5, -c6,  c1, -c4, -c7,  c2, -c3},
      {1.0, -c3,  c6,  c7, -c4,  c1, -c2,  c5},
      {1.0, -c1,  c2, -c3,  c4, -c5,  c6, -c7}};
    for (int i = 0; i < 64; ++i) {
      const int u = i >> 3, v = i & 7;
      for (int j = 0; j < 64; ++j) {
        const int x = j >> 3, y = j & 7;
        tr[i * 64 + j] = (float)(CX[x][u] * CX[y][v]);
      }
      const double au = (u == 0) ? alpha0 : 1.0;
      const double av = (v == 0) ? alpha0 : 1.0;
      sc[i] = (float)((au * av) * 0.25);
    }
    const int YT[64] = {
      16, 11, 10, 16, 24, 40, 51, 61,
      12, 12, 14, 19, 26, 58, 60, 55,
      14, 13, 16, 24, 40, 57, 69, 56,
      14, 17, 22, 29, 51, 87, 80, 62,
      18, 22, 37, 56, 68, 109, 103, 77,
      24, 35, 55, 64, 81, 104, 113, 92,
      49, 64, 78, 87, 103, 121, 120, 101,
      72, 92, 95, 98, 112, 100, 103, 99};
    const int CT[64] = {
      17, 18, 24, 47, 99, 99, 99, 99,
      18, 21, 26, 66, 99, 99, 99, 99,
      24, 26, 56, 99, 99, 99, 99, 99,
      47, 66, 99, 99, 99, 99, 99, 99,
      99, 99, 99, 99, 99, 99, 99, 99,
      99, 99, 99, 99, 99, 99, 99, 99,
      99, 99, 99, 99, 99, 99, 99, 99,
      99, 99, 99, 99, 99, 99, 99, 99};
    for (int i = 0; i < 64; ++i) {
      yq[i] = (float)YT[i];
      cq[i] = (float)CT[i];
    }
  }
};

__device__ constexpr Tab TT;

}  // namespace jc

// ---- contraction-proof f32 ops (asm boundary blocks FMA formation) ----
__device__ __forceinline__ float vmul(float a, float b) {
  float r; asm("v_mul_f32 %0, %1, %2" : "=v"(r) : "v"(a), "v"(b)); return r;
}
// SGPR x VGPR multiply: identical arithmetic, wave-uniform operand in SGPR.
__device__ __forceinline__ float vmulS(float s, float v) {
  float r; asm("v_mul_f32 %0, %1, %2" : "=v"(r) : "s"(s), "v"(v)); return r;
}
__device__ __forceinline__ float vadd(float a, float b) {
  float r; asm("v_add_f32 %0, %1, %2" : "=v"(r) : "v"(a), "v"(b)); return r;
}
__device__ __forceinline__ float vsubf(float a, float b) {  // a - b
  float r; asm("v_sub_f32 %0, %1, %2" : "=v"(r) : "v"(a), "v"(b)); return r;
}

// ---- by-value helpers (no references, no arrays) ----
__device__ __forceinline__ float yconv(float rv, float gv, float bv) {
  const float tR = vmul(rv, 255.0f);
  const float tG = vmul(gv, 255.0f);
  const float tB = vmul(bv, 255.0f);
  float a = vmul(tR, 0.299f);
  a = vadd(a, vmul(tG, 0.587f));
  a = vadd(a, vmul(tB, 0.114f));
  return vsubf(a, 128.0f);
}
__device__ __forceinline__ float chro_t(float rv, float gv, float bv,
                                        float kR, float kG, float kB) {
  const float tR = vmul(rv, 255.0f);
  const float tG = vmul(gv, 255.0f);
  const float tB = vmul(bv, 255.0f);
  float a = vmul(tR, kR);
  a = vadd(a, vmul(tG, kG));
  a = vadd(a, vmul(tB, kB));
  return vadd(a, 128.0f);
}
// 2x2 pool of chroma: row0 even/odd, row1 even/odd pixels (r,g,b each)
__device__ __forceinline__ float cpool(
    float r00, float g00, float b00, float r01, float g01, float b01,
    float r10, float g10, float b10, float r11, float g11, float b11,
    float kR, float kG, float kB) {
  const float p00 = chro_t(r00, g00, b00, kR, kG, kB);
  const float p01 = chro_t(r01, g01, b01, kR, kG, kB);
  const float p10 = chro_t(r10, g10, b10, kR, kG, kB);
  const float p11 = chro_t(r11, g11, b11, kR, kG, kB);
  const float s = vadd(vadd(vadd(p00, p01), p10), p11);
  return vsubf(vmul(s, 0.25f), 128.0f);
}

// ---- macro machinery: 64 named locals, straight-line code ----
#define REP64(F) F(0) F(1) F(2) F(3) F(4) F(5) F(6) F(7) \
  F(8) F(9) F(10) F(11) F(12) F(13) F(14) F(15) \
  F(16) F(17) F(18) F(19) F(20) F(21) F(22) F(23) \
  F(24) F(25) F(26) F(27) F(28) F(29) F(30) F(31) \
  F(32) F(33) F(34) F(35) F(36) F(37) F(38) F(39) \
  F(40) F(41) F(42) F(43) F(44) F(45) F(46) F(47) \
  F(48) F(49) F(50) F(51) F(52) F(53) F(54) F(55) \
  F(56) F(57) F(58) F(59) F(60) F(61) F(62) F(63)

#define DECLX(j) float X##j;

// Y pixel row rr -> 8 X values (by-name)
#define ROWY(rr, XA, XB, XC, XD, XE, XF, XG, XH) do { \
  const float* p0_ = rp + (rr) * 512; \
  const float4 r0_ = ((const float4*)p0_)[0]; \
  const float4 r1_ = ((const float4*)p0_)[1]; \
  const float4 g0_ = ((const float4*)(p0_ + 262144))[0]; \
  const float4 g1_ = ((const float4*)(p0_ + 262144))[1]; \
  const float4 b0_ = ((const float4*)(p0_ + 524288))[0]; \
  const float4 b1_ = ((const float4*)(p0_ + 524288))[1]; \
  XA = yconv(r0_.x, g0_.x, b0_.x); \
  XB = yconv(r0_.y, g0_.y, b0_.y); \
  XC = yconv(r0_.z, g0_.z, b0_.z); \
  XD = yconv(r0_.w, g0_.w, b0_.w); \
  XE = yconv(r1_.x, g1_.x, b1_.x); \
  XF = yconv(r1_.y, g1_.y, b1_.y); \
  XG = yconv(r1_.z, g1_.z, b1_.z); \
  XH = yconv(r1_.w, g1_.w, b1_.w); \
} while (0)

// chroma pooled row q (from pixel rows 2q, 2q+1; 16 px) -> 8 X values
#define CROWQ(q, XA, XB, XC, XD, XE, XF, XG, XH) do { \
  const float* p0_ = rp + (2 * (q)) * 512; \
  const float4 ra0 = ((const float4*)p0_)[0]; \
  const float4 ra1 = ((const float4*)p0_)[1]; \
  const float4 ra2 = ((const float4*)p0_)[2]; \
  const float4 ra3 = ((const float4*)p0_)[3]; \
  const float4 rb0 = ((const float4*)(p0_ + 512))[0]; \
  const float4 rb1 = ((const float4*)(p0_ + 512))[1]; \
  const float4 rb2 = ((const float4*)(p0_ + 512))[2]; \
  const float4 rb3 = ((const float4*)(p0_ + 512))[3]; \
  const float4 ga0 = ((const float4*)(p0_ + 262144))[0]; \
  const float4 ga1 = ((const float4*)(p0_ + 262144))[1]; \
  const float4 ga2 = ((const float4*)(p0_ + 262144))[2]; \
  const float4 ga3 = ((const float4*)(p0_ + 262144))[3]; \
  const float4 gb0 = ((const float4*)(p0_ + 262144 + 512))[0]; \
  const float4 gb1 = ((const float4*)(p0_ + 262144 + 512))[1]; \
  const float4 gb2 = ((const float4*)(p0_ + 262144 + 512))[2]; \
  const float4 gb3 = ((const float4*)(p0_ + 262144 + 512))[3]; \
  const float4 ba0 = ((const float4*)(p0_ + 524288))[0]; \
  const float4 ba1 = ((const float4*)(p0_ + 524288))[1]; \
  const float4 ba2 = ((const float4*)(p0_ + 524288))[2]; \
  const float4 ba3 = ((const float4*)(p0_ + 524288))[3]; \
  const float4 bb0 = ((const float4*)(p0_ + 524288 + 512))[0]; \
  const float4 bb1 = ((const float4*)(p0_ + 524288 + 512))[1]; \
  const float4 bb2 = ((const float4*)(p0_ + 524288 + 512))[2]; \
  const float4 bb3 = ((const float4*)(p0_ + 524288 + 512))[3]; \
  XA = cpool(ra0.x, ga0.x, ba0.x, ra0.y, ga0.y, ba0.y, \
             rb0.x, gb0.x, bb0.x, rb0.y, gb0.y, bb0.y, kR, kG, kB); \
  XB = cpool(ra0.z, ga0.z, ba0.z, ra0.w, ga0.w, ba0.w, \
             rb0.z, gb0.z, bb0.z, rb0.w, gb0.w, bb0.w, kR, kG, kB); \
  XC = cpool(ra1.x, ga1.x, ba1.x, ra1.y, ga1.y, ba1.y, \
             rb1.x, gb1.x, bb1.x, rb1.y, gb1.y, bb1.y, kR, kG, kB); \
  XD = cpool(ra1.z, ga1.z, ba1.z, ra1.w, ga1.w, ba1.w, \
             rb1.z, gb1.z, bb1.z, rb1.w, gb1.w, bb1.w, kR, kG, kB); \
  XE = cpool(ra2.x, ga2.x, ba2.x, ra2.y, ga2.y, ba2.y, \
             rb2.x, gb2.x, bb2.x, rb2.y, gb2.y, bb2.y, kR, kG, kB); \
  XF = cpool(ra2.z, ga2.z, ba2.z, ra2.w, ga2.w, ba2.w, \
             rb2.z, gb2.z, bb2.z, rb2.w, gb2.w, bb2.w, kR, kG, kB); \
  XG = cpool(ra3.x, ga3.x, ba3.x, ra3.y, ga3.y, ba3.y, \
             rb3.x, gb3.x, bb3.x, rb3.y, gb3.y, bb3.y, kR, kG, kB); \
  XH = cpool(ra3.z, ga3.z, ba3.z, ra3.w, ga3.w, ba3.w, \
             rb3.z, gb3.z, bb3.z, rb3.w, gb3.w, bb3.w, kR, kG, kB); \
} while (0)

// one DCT output: 64-step rn chain in row-major j order (MUST stay ascending)
#define MACJ(j) acc = vadd(acc, vmulS(trow[j], X##j));
#define DCT1(iexpr, dest) do { \
  const int i_ = (iexpr); \
  const float* __restrict__ trow = jc::TT.tr + i_ * 64; \
  float acc = 0.0f; \
  REP64(MACJ) \
  dest = rintf(__fdiv_rn(vmulS(jc::TT.sc[i_], acc), qt[i_])); \
} while (0)

// grid: 768 wg x 256 thr = 3072 waves; wave = 64 blocks of one kind.
// per image (96 waves): wv 0..63 Y (block row wv, col=lane),
//                       wv 64..79 Cb (blocks m*64+lane), wv 80..95 Cr.
__global__ __launch_bounds__(256, 3)
void jpeg_kernel(const float* __restrict__ img, float* __restrict__ out) {
  __shared__ float S[4][64][20];  // per-wave transpose slab (verified r11)

  const int t = threadIdx.x;
  const int lane = t & 63;
  const int w = __builtin_amdgcn_readfirstlane(t >> 6);  // uniform wave id
  const int gw = blockIdx.x * 4 + w;
  const int im = gw / 96;   // image 0..31 (uniform -> scalar div)
  const int wv = gw - im * 96;

  const float* base = img + (size_t)im * 786432;  // 3*512*512

  REP64(DECLX)      // float X0..X63 -- named locals, nothing else
  unsigned wbase;   // wave-level output base (wave's 64 blocks contiguous)
  bool isY;

  if (wv < 64) {
    // ---------------- Y wave: lane owns Y block (row wv, col lane) ----------
    isY = true;
    const float* rp = base + (wv * 8) * 512 + lane * 8;
    ROWY(0, X0,  X1,  X2,  X3,  X4,  X5,  X6,  X7);
    ROWY(1, X8,  X9,  X10, X11, X12, X13, X14, X15);
    ROWY(2, X16, X17, X18, X19, X20, X21, X22, X23);
    ROWY(3, X24, X25, X26, X27, X28, X29, X30, X31);
    ROWY(4, X32, X33, X34, X35, X36, X37, X38, X39);
    ROWY(5, X40, X41, X42, X43, X44, X45, X46, X47);
    ROWY(6, X48, X49, X50, X51, X52, X53, X54, X55);
    ROWY(7, X56, X57, X58, X59, X60, X61, X62, X63);
    wbase = (unsigned)(im * 262144 + wv * 4096);
  } else {
    // ------------- chroma wave: lane owns one Cb or Cr block ---------------
    isY = false;
    const int cwv = wv - 64;
    const bool isCb = (cwv < 16);
    const int m = cwv & 15;
    const int cy = 2 * m + (lane >> 5);  // chroma block row 0..31
    const int cx = lane & 31;            // chroma block col 0..31
    const float kR = isCb ? -0.168736f : 0.5f;
    const float kG = isCb ? -0.331264f : -0.418688f;
    const float kB = isCb ? 0.5f : -0.081312f;
    const float* rp = base + (cy * 16) * 512 + cx * 16;
    CROWQ(0, X0,  X1,  X2,  X3,  X4,  X5,  X6,  X7);
    CROWQ(1, X8,  X9,  X10, X11, X12, X13, X14, X15);
    CROWQ(2, X16, X17, X18, X19, X20, X21, X22, X23);
    CROWQ(3, X24, X25, X26, X27, X28, X29, X30, X31);
    CROWQ(4, X32, X33, X34, X35, X36, X37, X38, X39);
    CROWQ(5, X40, X41, X42, X43, X44, X45, X46, X47);
    CROWQ(6, X48, X49, X50, X51, X52, X53, X54, X55);
    CROWQ(7, X56, X57, X58, X59, X60, X61, X62, X63);
    wbase = 8388608u + (isCb ? 0u : 2097152u) + (unsigned)(im * 65536 + m * 4096);
  }

  // ------------- DCT + quantize + LDS-transposed coalesced store ----------
  const float* __restrict__ qt = isY ? jc::TT.yq : jc::TT.cq;  // uniform
  float* wout = out + wbase;

#pragma unroll 1
  for (int f = 0; f < 4; ++f) {          // slab: coeffs f*16 .. f*16+15
#pragma unroll 1
    for (int g = 0; g < 4; ++g) {        // quad of outputs within slab
      const int ib = f * 16 + g * 4;
      float o0, o1, o2, o3;
      DCT1(ib + 0, o0);
      DCT1(ib + 1, o1);
      DCT1(ib + 2, o2);
      DCT1(ib + 3, o3);
      float4 v4; v4.x = o0; v4.y = o1; v4.z = o2; v4.w = o3;
      *(float4*)&S[w][lane][g * 4] = v4;  // ds_write_b128, wave-private
    }
    // transposed read + full-64B-line stores (wave-private, DS in-order)
#pragma unroll
    for (int k = 0; k < 4; ++k) {
      const int B = k * 16 + (lane >> 2);       // block within wave
      const int e0 = (lane & 3) * 4;            // coeff quad within slab
      const float4 vv = *(const float4*)&S[w][B][e0];
      *(float4*)&wout[B * 64 + f * 16 + e0] = vv;
    }
  }
}

extern "C" void kernel_launch(void* const* d_in, const int* in_sizes, int n_in,
                              void* d_out, int out_size, void* d_ws, size_t ws_size,
                              hipStream_t stream) {
  (void)in_sizes; (void)n_in; (void)d_ws; (void)ws_size; (void)out_size;
  const float* img = (const float*)d_in[0];
  float* out = (float*)d_out;
  jpeg_kernel<<<dim3(768), dim3(256), 0, stream>>>(img, out);
}

// Round 6
// 308.014 us; speedup vs baseline: 1.1406x; 1.0273x over previous
//
#include <hip/hip_runtime.h>
#include <cmath>

// ---------------------------------------------------------------------------
// JPEG compress (YCbCr + 2x2 chroma pool + 8x8 DCT + quantize/round).
//
// Numerics contract (VERIFIED r4..r12, absmax 0.0): f32 end-to-end, every
// accumulation step is mul-then-add with TWO roundings (no FMA). All
// value-path mul/add/sub are inline-asm v_mul_f32 / v_add_f32 / v_sub_f32
// (asm boundary blocks FMA formation). fdiv/rint stay as builtins.
//
// Recipe per output (DO NOT CHANGE):
//   t_c   = rn(x_c * 255)
//   y     = chain c=R,G,B: a = rn(a + rn(t_c*k_c));  X = rn(a - 128)
//   cb/cr = same chain + 128; pool ((p00+p01)+p10)+p11 * 0.25; - 128
//   dct_i = 64-step chain j=(x,y) row-major from 0: a = rn(a + rn(T_ij*X_j))
//   outv  = rintf( rn( rn(sc_i * dct_i) / q_i ) )
//
// R13 = r8 shell + register-X + REAL SGPR-T:
//  - r12's 3x VALU bloat diagnosed: "s"-constraint on loads from __device__
//    (addrspace-1) table -> divergent-marked -> per-lane global_load +
//    v_readfirstlane per MAC (4096/wave). FIX: table is __constant__
//    (addrspace-4): uniform-pointer loads select s_load unconditionally.
//  - r8's LDS-broadcast cost killed: phase 2 is lane=block, i wave-uniform.
//    wave0/1 = Y blocks 0-63, i in [0,32)/[32,64); wave2/3 = 32 chroma
//    blocks on lanes 0-31. Lane reads its OWN block from LDS once
//    (16 ds_read_b128, stride-68 rows = 2-way banks, free) into NAMED
//    registers X0..X63 (r12-proven promotion).
//  - grid 2048 x 256 (r8 occupancy), phase 1 staging verbatim r8
//    (one pixel read, FETCH 49MB), stores via r11/r12-verified LDS slab
//    transpose OVERLAID on Xs after a barrier (LDS stays 26112B).
// ---------------------------------------------------------------------------

namespace jc {

constexpr double c1 = 0.98078528040323044912618223613424;
constexpr double c2 = 0.92387953251128675612818318939679;
constexpr double c3 = 0.83146961230254523707878837761791;
constexpr double c4 = 0.70710678118654752440084436210485;
constexpr double c5 = 0.55557023301960222474283081394853;
constexpr double c6 = 0.38268343236508977172845998403040;
constexpr double c7 = 0.19509032201612826784828486847702;
constexpr double alpha0 = 0.70710678118654746171979706919384;  // 1/sqrt(2)

struct Tab {
  float tr[4096];  // ROW-major: tr[i*64+j] = f32(CX[x][u]*CX[y][v]), i=(u,v), j=(x,y)
  float sc[64];    // f32(f64(alpha_u*alpha_v)*0.25)
  float yq[64];
  float cq[64];
  constexpr Tab() : tr(), sc(), yq(), cq() {
    const double CX[8][8] = {
      {1.0,  c1,  c2,  c3,  c4,  c5,  c6,  c7},
      {1.0,  c3,  c6, -c7, -c4, -c1, -c2, -c5},
      {1.0,  c5, -c6, -c1, -c4,  c7,  c2,  c3},
      {1.0,  c7, -c2, -c5,  c4,  c3, -c6, -c1},
      {1.0, -c7, -c2,  c5,  c4, -c3, -c6,  c1},
      {1.0, -c5, -c6,  c1, -c4, -c7,  c2, -c3},
      {1.0, -c3,  c6,  c7, -c4,  c1, -c2,  c5},
      {1.0, -c1,  c2, -c3,  c4, -c5,  c6, -c7}};
    for (int i = 0; i < 64; ++i) {
      const int u = i >> 3, v = i & 7;
      for (int j = 0; j < 64; ++j) {
        const int x = j >> 3, y = j & 7;
        tr[i * 64 + j] = (float)(CX[x][u] * CX[y][v]);
      }
      const double au = (u == 0) ? alpha0 : 1.0;
      const double av = (v == 0) ? alpha0 : 1.0;
      sc[i] = (float)((au * av) * 0.25);
    }
    const int YT[64] = {
      16, 11, 10, 16, 24, 40, 51, 61,
      12, 12, 14, 19, 26, 58, 60, 55,
      14, 13, 16, 24, 40, 57, 69, 56,
      14, 17, 22, 29, 51, 87, 80, 62,
      18, 22, 37, 56, 68, 109, 103, 77,
      24, 35, 55, 64, 81, 104, 113, 92,
      49, 64, 78, 87, 103, 121, 120, 101,
      72, 92, 95, 98, 112, 100, 103, 99};
    const int CT[64] = {
      17, 18, 24, 47, 99, 99, 99, 99,
      18, 21, 26, 66, 99, 99, 99, 99,
      24, 26, 56, 99, 99, 99, 99, 99,
      47, 66, 99, 99, 99, 99, 99, 99,
      99, 99, 99, 99, 99, 99, 99, 99,
      99, 99, 99, 99, 99, 99, 99, 99,
      99, 99, 99, 99, 99, 99, 99, 99,
      99, 99, 99, 99, 99, 99, 99, 99};
    for (int i = 0; i < 64; ++i) {
      yq[i] = (float)YT[i];
      cq[i] = (float)CT[i];
    }
  }
};

}  // namespace jc

// __constant__ => addrspace(4): uniform-pointer loads select s_load (SMEM),
// so the "s" asm constraint below is satisfied without readfirstlane.
__constant__ jc::Tab TT;

// ---- contraction-proof f32 ops (asm boundary blocks FMA formation) ----
__device__ __forceinline__ float vmul(float a, float b) {
  float r; asm("v_mul_f32 %0, %1, %2" : "=v"(r) : "v"(a), "v"(b)); return r;
}
// SGPR x VGPR multiply: identical arithmetic (same v_mul_f32).
__device__ __forceinline__ float vmulS(float s, float v) {
  float r; asm("v_mul_f32 %0, %1, %2" : "=v"(r) : "s"(s), "v"(v)); return r;
}
__device__ __forceinline__ float vadd(float a, float b) {
  float r; asm("v_add_f32 %0, %1, %2" : "=v"(r) : "v"(a), "v"(b)); return r;
}
__device__ __forceinline__ float vsubf(float a, float b) {  // a - b
  float r; asm("v_sub_f32 %0, %1, %2" : "=v"(r) : "v"(a), "v"(b)); return r;
}

// chroma chain from pre-scaled t values (tR=rn(R*255) etc.), + 128 shift
__device__ __forceinline__ float chro_t(float tR, float tG, float tB,
                                        float kR, float kG, float kB) {
  float a = vmul(tR, kR);
  a = vadd(a, vmul(tG, kG));
  a = vadd(a, vmul(tB, kB));
  return vadd(a, 128.0f);
}

// ---- named-scalar machinery (r12-proven promotion) ----
#define REP64(F) F(0) F(1) F(2) F(3) F(4) F(5) F(6) F(7) \
  F(8) F(9) F(10) F(11) F(12) F(13) F(14) F(15) \
  F(16) F(17) F(18) F(19) F(20) F(21) F(22) F(23) \
  F(24) F(25) F(26) F(27) F(28) F(29) F(30) F(31) \
  F(32) F(33) F(34) F(35) F(36) F(37) F(38) F(39) \
  F(40) F(41) F(42) F(43) F(44) F(45) F(46) F(47) \
  F(48) F(49) F(50) F(51) F(52) F(53) F(54) F(55) \
  F(56) F(57) F(58) F(59) F(60) F(61) F(62) F(63)

#define DECLX(j) float X##j;

// load 4 X from this lane's block row in LDS into named regs
#define LDX(k, XA, XB, XC, XD) do { \
  const float4 v_ = *(const float4*)&LDSbuf[blk * 68 + 4 * (k)]; \
  XA = v_.x; XB = v_.y; XC = v_.z; XD = v_.w; \
} while (0)

// one DCT output: 64-step rn chain in row-major j order (MUST stay ascending)
#define MACJ(j) acc = vadd(acc, vmulS(trow[j], X##j));
#define DCT1(iexpr, dest) do { \
  const int i_ = (iexpr); \
  const float* trow = TT.tr + i_ * 64; \
  float acc = 0.0f; \
  REP64(MACJ) \
  dest = rintf(__fdiv_rn(vmulS(TT.sc[i_], acc), qt[i_])); \
} while (0)

// grid: 2048 wg x 256 thr. wg = 64x64-px region of one image:
// 64 Y + 16 Cb + 16 Cr blocks, staged from ONE pixel read (r8 phase 1).
// Phase 2: wave0/1 -> Y blocks (lane=block), i in [0,32)/[32,64);
//          wave2/3 -> chroma blocks 64+lane (lanes 0-31), same i split.
__global__ __launch_bounds__(256, 4)
void jpeg_kernel(const float* __restrict__ img, float* __restrict__ out) {
  __shared__ float LDSbuf[96 * 68];  // Xs[96][68]; slab overlays after barrier

  const int t = threadIdx.x;
  const int lane = t & 63;
  const int w = __builtin_amdgcn_readfirstlane(t >> 6);  // uniform wave id
  const int wid = blockIdx.x;
  const int b = wid >> 6;   // batch 0..31
  const int r = wid & 63;   // region 0..63 (8x8 grid of 64x64-px regions)

  // ================= phase 1: merged staging (r8 verbatim) =================
  {
    const int yb = t & 63;   // Y block 0..63 within region
    const int q = t >> 6;    // row-pair 0..3 within the Y block
    const int by = yb >> 3, bx = yb & 7;
    const int prow = (r >> 3) * 64 + by * 8 + 2 * q;  // global pixel row
    const int pcol = (r & 7) * 64 + bx * 8;
    const float* rp = img + (size_t)b * 786432 + (size_t)prow * 512 + pcol;

    float tv[3][2][8];  // rn(px*255): channel, row-in-pair, col
#pragma unroll
    for (int c = 0; c < 3; ++c) {
#pragma unroll
      for (int rr = 0; rr < 2; ++rr) {
        const float* p0 = rp + c * 262144 + rr * 512;
        const float4 va = *(const float4*)(p0);
        const float4 vb = *(const float4*)(p0 + 4);
        tv[c][rr][0] = vmul(va.x, 255.0f);
        tv[c][rr][1] = vmul(va.y, 255.0f);
        tv[c][rr][2] = vmul(va.z, 255.0f);
        tv[c][rr][3] = vmul(va.w, 255.0f);
        tv[c][rr][4] = vmul(vb.x, 255.0f);
        tv[c][rr][5] = vmul(vb.y, 255.0f);
        tv[c][rr][6] = vmul(vb.z, 255.0f);
        tv[c][rr][7] = vmul(vb.w, 255.0f);
      }
    }
    // --- Y: 16 values -> Xs[yb][16q .. 16q+15] (j = (2q+rr)*8 + y) ---
#pragma unroll
    for (int rr = 0; rr < 2; ++rr) {
#pragma unroll
      for (int y = 0; y < 8; ++y) {
        float a = vmul(tv[0][rr][y], 0.299f);
        a = vadd(a, vmul(tv[1][rr][y], 0.587f));
        a = vadd(a, vmul(tv[2][rr][y], 0.114f));
        LDSbuf[yb * 68 + 16 * q + rr * 8 + y] = vsubf(a, 128.0f);
      }
    }
    // --- chroma: this thread owns chroma row lcr, cols 4bx..4bx+3 ---
    const int lcr = 4 * by + q;  // 0..31 within region
#pragma unroll
    for (int pc = 0; pc < 4; ++pc) {
      const int lcc = 4 * bx + pc;
      const int crow = 64 + ((lcr >> 3) * 4 + (lcc >> 3));  // Cb block row
      const int cell = (lcr & 7) * 8 + (lcc & 7);
      const int e = 2 * pc, o = 2 * pc + 1;
      // Cb
      {
        const float p00 = chro_t(tv[0][0][e], tv[1][0][e], tv[2][0][e], -0.168736f, -0.331264f, 0.5f);
        const float p01 = chro_t(tv[0][0][o], tv[1][0][o], tv[2][0][o], -0.168736f, -0.331264f, 0.5f);
        const float p10 = chro_t(tv[0][1][e], tv[1][1][e], tv[2][1][e], -0.168736f, -0.331264f, 0.5f);
        const float p11 = chro_t(tv[0][1][o], tv[1][1][o], tv[2][1][o], -0.168736f, -0.331264f, 0.5f);
        const float s = vadd(vadd(vadd(p00, p01), p10), p11);
        LDSbuf[crow * 68 + cell] = vsubf(vmul(s, 0.25f), 128.0f);
      }
      // Cr
      {
        const float p00 = chro_t(tv[0][0][e], tv[1][0][e], tv[2][0][e], 0.5f, -0.418688f, -0.081312f);
        const float p01 = chro_t(tv[0][0][o], tv[1][0][o], tv[2][0][o], 0.5f, -0.418688f, -0.081312f);
        const float p10 = chro_t(tv[0][1][e], tv[1][1][e], tv[2][1][e], 0.5f, -0.418688f, -0.081312f);
        const float p11 = chro_t(tv[0][1][o], tv[1][1][o], tv[2][1][o], 0.5f, -0.418688f, -0.081312f);
        const float s = vadd(vadd(vadd(p00, p01), p10), p11);
        LDSbuf[(crow + 16) * 68 + cell] = vsubf(vmul(s, 0.25f), 128.0f);
      }
    }
  }

  // ================= phase 2: lane=block, i wave-uniform =================
  const int ibase = (w & 1) * 32;          // i range of this wave
  const bool chro = (w >= 2);
  const bool active = (!chro) || (lane < 32);
  const int blk = chro ? (64 + (lane & 31)) : lane;  // Xs row of my block
  const float* qt = chro ? TT.cq : TT.yq;  // uniform (constant AS)

  REP64(DECLX)  // X0..X63 named locals

  __syncthreads();  // staging complete

  if (active) {
    LDX(0,  X0,  X1,  X2,  X3);
    LDX(1,  X4,  X5,  X6,  X7);
    LDX(2,  X8,  X9,  X10, X11);
    LDX(3,  X12, X13, X14, X15);
    LDX(4,  X16, X17, X18, X19);
    LDX(5,  X20, X21, X22, X23);
    LDX(6,  X24, X25, X26, X27);
    LDX(7,  X28, X29, X30, X31);
    LDX(8,  X32, X33, X34, X35);
    LDX(9,  X36, X37, X38, X39);
    LDX(10, X40, X41, X42, X43);
    LDX(11, X44, X45, X46, X47);
    LDX(12, X48, X49, X50, X51);
    LDX(13, X52, X53, X54, X55);
    LDX(14, X56, X57, X58, X59);
    LDX(15, X60, X61, X62, X63);
  }

  __syncthreads();  // all X-loads done; Xs memory now reusable as slab

  // slab: S(w,row,e) = LDSbuf[(w*64+row)*20 + e]   (max 5120 floats < 6528)
  const int ybase = b * 4096 + (r >> 3) * 512 + (r & 7) * 8;
  const int cbase = b * 1024 + (r >> 3) * 128 + (r & 7) * 4;

#pragma unroll 1
  for (int f = 0; f < 2; ++f) {            // two 16-coeff slabs per wave
    if (active) {
#pragma unroll 1
      for (int g = 0; g < 4; ++g) {        // quad of outputs within slab
        const int ib = ibase + f * 16 + g * 4;
        float o0, o1, o2, o3;
        DCT1(ib + 0, o0);
        DCT1(ib + 1, o1);
        DCT1(ib + 2, o2);
        DCT1(ib + 3, o3);
        float4 v4; v4.x = o0; v4.y = o1; v4.z = o2; v4.w = o3;
        *(float4*)&LDSbuf[(w * 64 + lane) * 20 + g * 4] = v4;  // wave-private
      }
    }
    // transposed read + full-64B-line stores (wave-private slab, DS in-order)
    const int co = ibase + f * 16;         // coeff base within block
    if (!chro) {
#pragma unroll
      for (int k = 0; k < 4; ++k) {        // 64 blocks x 16 coeffs
        const int B = k * 16 + (lane >> 2);
        const int e0 = (lane & 3) * 4;
        const float4 vv = *(const float4*)&LDSbuf[(w * 64 + B) * 20 + e0];
        const unsigned ob = (unsigned)(ybase + (B >> 3) * 64 + (B & 7));
        *(float4*)&out[(ob << 6) + (unsigned)(co + e0)] = vv;  // full line
      }
    } else {
#pragma unroll
      for (int k = 0; k < 2; ++k) {        // 32 blocks x 16 coeffs
        const int idx = k * 64 + lane;
        const int B = idx >> 2;            // 0..31 (16 Cb then 16 Cr)
        const int e0 = (idx & 3) * 4;
        const float4 vv = *(const float4*)&LDSbuf[(w * 64 + B) * 20 + e0];
        const int cc = B & 15;
        const unsigned ob = 8388608u + (B >= 16 ? 2097152u : 0u) +
            (((unsigned)(cbase + (cc >> 2) * 32 + (cc & 3))) << 6);
        *(float4*)&out[ob + (unsigned)(co + e0)] = vv;  // full line
      }
    }
  }
}

extern "C" void kernel_launch(void* const* d_in, const int* in_sizes, int n_in,
                              void* d_out, int out_size, void* d_ws, size_t ws_size,
                              hipStream_t stream) {
  (void)in_sizes; (void)n_in; (void)d_ws; (void)ws_size; (void)out_size;
  const float* img = (const float*)d_in[0];
  float* out = (float*)d_out;
  jpeg_kernel<<<dim3(2048), dim3(256), 0, stream>>>(img, out);
}

// Round 7
// 192.757 us; speedup vs baseline: 1.8226x; 1.5979x over previous
//
#include <hip/hip_runtime.h>
#include <cmath>

// ---------------------------------------------------------------------------
// JPEG compress (YCbCr + 2x2 chroma pool + 8x8 DCT + quantize/round).
//
// Numerics contract (VERIFIED r4..r13, absmax 0.0): f32 end-to-end, every
// accumulation step is mul-then-add with TWO roundings (no FMA). Value-path
// ops are explicit v_mul_f32 / v_add_f32 / v_sub_f32 (asm). fdiv/rint are
// __fdiv_rn / rintf builtins (verified). First DCT step uses rn(0+x)=x.
//
// Recipe per output (DO NOT CHANGE):
//   t_c   = rn(x_c * 255)
//   y     = chain c=R,G,B: a = rn(a + rn(t_c*k_c));  X = rn(a - 128)
//   cb/cr = same chain + 128; pool ((p00+p01)+p10)+p11 * 0.25; - 128
//   dct_i = 64-step chain j=(x,y) row-major from 0: a = rn(a + rn(T_ij*X_j))
//   outv  = rintf( rn( rn(sc_i * dct_i) / q_i ) )
//
// R13->R14: MEGA-ASM DCT. Four rounds proved the allocator will not keep a
// 64-float working set in VGPRs via source hints (r13: VGPR=48, X remat'd
// from LDS per MAC -> 41% VALUBusy). The only residency contract it must
// honor is inline-asm hard registers. Each 16-output slab is ONE asm block:
//   ds_read_b128 x16 -> X in v[40:103] (hard), per output 4x s_load_dwordx16
//   -> T row in s[36:99] (constant-AS SMEM, wave-uniform, free), waitcnt,
//   128 VOP2 MAC chain (exact mandated order), acc -> "=&v" output.
// Self-contained (X re-read per block) => no cross-asm persistence hazard.
// Staging / slab-transpose stores / addressing are r13-verified verbatim.
// ---------------------------------------------------------------------------

namespace jc {

constexpr double c1 = 0.98078528040323044912618223613424;
constexpr double c2 = 0.92387953251128675612818318939679;
constexpr double c3 = 0.83146961230254523707878837761791;
constexpr double c4 = 0.70710678118654752440084436210485;
constexpr double c5 = 0.55557023301960222474283081394853;
constexpr double c6 = 0.38268343236508977172845998403040;
constexpr double c7 = 0.19509032201612826784828486847702;
constexpr double alpha0 = 0.70710678118654746171979706919384;  // 1/sqrt(2)

struct Tab {
  float tr[4096];  // ROW-major: tr[i*64+j], i=(u,v), j=(x,y)
  float sc[64];
  float yq[64];
  float cq[64];
  constexpr Tab() : tr(), sc(), yq(), cq() {
    const double CX[8][8] = {
      {1.0,  c1,  c2,  c3,  c4,  c5,  c6,  c7},
      {1.0,  c3,  c6, -c7, -c4, -c1, -c2, -c5},
      {1.0,  c5, -c6, -c1, -c4,  c7,  c2,  c3},
      {1.0,  c7, -c2, -c5,  c4,  c3, -c6, -c1},
      {1.0, -c7, -c2,  c5,  c4, -c3, -c6,  c1},
      {1.0, -c5, -c6,  c1, -c4, -c7,  c2, -c3},
      {1.0, -c3,  c6,  c7, -c4,  c1, -c2,  c5},
      {1.0, -c1,  c2, -c3,  c4, -c5,  c6, -c7}};
    for (int i = 0; i < 64; ++i) {
      const int u = i >> 3, v = i & 7;
      for (int j = 0; j < 64; ++j) {
        const int x = j >> 3, y = j & 7;
        tr[i * 64 + j] = (float)(CX[x][u] * CX[y][v]);
      }
      const double au = (u == 0) ? alpha0 : 1.0;
      const double av = (v == 0) ? alpha0 : 1.0;
      sc[i] = (float)((au * av) * 0.25);
    }
    const int YT[64] = {
      16, 11, 10, 16, 24, 40, 51, 61,
      12, 12, 14, 19, 26, 58, 60, 55,
      14, 13, 16, 24, 40, 57, 69, 56,
      14, 17, 22, 29, 51, 87, 80, 62,
      18, 22, 37, 56, 68, 109, 103, 77,
      24, 35, 55, 64, 81, 104, 113, 92,
      49, 64, 78, 87, 103, 121, 120, 101,
      72, 92, 95, 98, 112, 100, 103, 99};
    const int CT[64] = {
      17, 18, 24, 47, 99, 99, 99, 99,
      18, 21, 26, 66, 99, 99, 99, 99,
      24, 26, 56, 99, 99, 99, 99, 99,
      47, 66, 99, 99, 99, 99, 99, 99,
      99, 99, 99, 99, 99, 99, 99, 99,
      99, 99, 99, 99, 99, 99, 99, 99,
      99, 99, 99, 99, 99, 99, 99, 99,
      99, 99, 99, 99, 99, 99, 99, 99};
    for (int i = 0; i < 64; ++i) {
      yq[i] = (float)YT[i];
      cq[i] = (float)CT[i];
    }
  }
};

}  // namespace jc

__constant__ jc::Tab TT;  // addrspace(4): uniform loads are true s_load SMEM

// ---- contraction-proof f32 ops (asm boundary blocks FMA formation) ----
__device__ __forceinline__ float vmul(float a, float b) {
  float r; asm("v_mul_f32 %0, %1, %2" : "=v"(r) : "v"(a), "v"(b)); return r;
}
__device__ __forceinline__ float vadd(float a, float b) {
  float r; asm("v_add_f32 %0, %1, %2" : "=v"(r) : "v"(a), "v"(b)); return r;
}
__device__ __forceinline__ float vsubf(float a, float b) {  // a - b
  float r; asm("v_sub_f32 %0, %1, %2" : "=v"(r) : "v"(a), "v"(b)); return r;
}

__device__ __forceinline__ float chro_t(float tR, float tG, float tB,
                                        float kR, float kG, float kB) {
  float a = vmul(tR, kR);
  a = vadd(a, vmul(tG, kG));
  a = vadd(a, vmul(tB, kB));
  return vadd(a, 128.0f);
}

// quantize: rintf( rn( rn(sc*acc) / q ) )  -- verified op sequence
__device__ __forceinline__ float q4(float acc, float sc, float q) {
  return rintf(__fdiv_rn(vmul(sc, acc), q));
}

// ================= mega-asm DCT machinery =================
// X block resident in v[40:103] (X_j <-> v(40+j)); T row in s[36:99]
// (T_j <-> s(36+j)); v104 = mul temp.

#define MP(AK, SJ, VJ) \
  "v_mul_f32 v104, " SJ ", " VJ "\n\t" \
  "v_add_f32 " AK ", " AK ", v104\n\t"

#define CHAIN(AK) \
  "v_mul_f32 " AK ", s36, v40\n\t" \
  MP(AK,"s37","v41") MP(AK,"s38","v42") MP(AK,"s39","v43") MP(AK,"s40","v44") \
  MP(AK,"s41","v45") MP(AK,"s42","v46") MP(AK,"s43","v47") \
  MP(AK,"s44","v48") MP(AK,"s45","v49") MP(AK,"s46","v50") MP(AK,"s47","v51") \
  MP(AK,"s48","v52") MP(AK,"s49","v53") MP(AK,"s50","v54") MP(AK,"s51","v55") \
  MP(AK,"s52","v56") MP(AK,"s53","v57") MP(AK,"s54","v58") MP(AK,"s55","v59") \
  MP(AK,"s56","v60") MP(AK,"s57","v61") MP(AK,"s58","v62") MP(AK,"s59","v63") \
  MP(AK,"s60","v64") MP(AK,"s61","v65") MP(AK,"s62","v66") MP(AK,"s63","v67") \
  MP(AK,"s64","v68") MP(AK,"s65","v69") MP(AK,"s66","v70") MP(AK,"s67","v71") \
  MP(AK,"s68","v72") MP(AK,"s69","v73") MP(AK,"s70","v74") MP(AK,"s71","v75") \
  MP(AK,"s72","v76") MP(AK,"s73","v77") MP(AK,"s74","v78") MP(AK,"s75","v79") \
  MP(AK,"s76","v80") MP(AK,"s77","v81") MP(AK,"s78","v82") MP(AK,"s79","v83") \
  MP(AK,"s80","v84") MP(AK,"s81","v85") MP(AK,"s82","v86") MP(AK,"s83","v87") \
  MP(AK,"s84","v88") MP(AK,"s85","v89") MP(AK,"s86","v90") MP(AK,"s87","v91") \
  MP(AK,"s88","v92") MP(AK,"s89","v93") MP(AK,"s90","v94") MP(AK,"s91","v95") \
  MP(AK,"s92","v96") MP(AK,"s93","v97") MP(AK,"s94","v98") MP(AK,"s95","v99") \
  MP(AK,"s96","v100") MP(AK,"s97","v101") MP(AK,"s98","v102") MP(AK,"s99","v103")

#define ROWM(AK, O0, O1, O2, O3) \
  "s_load_dwordx16 s[36:51], %[tp], " O0 "\n\t" \
  "s_load_dwordx16 s[52:67], %[tp], " O1 "\n\t" \
  "s_load_dwordx16 s[68:83], %[tp], " O2 "\n\t" \
  "s_load_dwordx16 s[84:99], %[tp], " O3 "\n\t" \
  "s_waitcnt lgkmcnt(0)\n\t" \
  CHAIN(AK)

#define XLOAD \
  "ds_read_b128 v[40:43], %[xa] offset:0\n\t" \
  "ds_read_b128 v[44:47], %[xa] offset:16\n\t" \
  "ds_read_b128 v[48:51], %[xa] offset:32\n\t" \
  "ds_read_b128 v[52:55], %[xa] offset:48\n\t" \
  "ds_read_b128 v[56:59], %[xa] offset:64\n\t" \
  "ds_read_b128 v[60:63], %[xa] offset:80\n\t" \
  "ds_read_b128 v[64:67], %[xa] offset:96\n\t" \
  "ds_read_b128 v[68:71], %[xa] offset:112\n\t" \
  "ds_read_b128 v[72:75], %[xa] offset:128\n\t" \
  "ds_read_b128 v[76:79], %[xa] offset:144\n\t" \
  "ds_read_b128 v[80:83], %[xa] offset:160\n\t" \
  "ds_read_b128 v[84:87], %[xa] offset:176\n\t" \
  "ds_read_b128 v[88:91], %[xa] offset:192\n\t" \
  "ds_read_b128 v[92:95], %[xa] offset:208\n\t" \
  "ds_read_b128 v[96:99], %[xa] offset:224\n\t" \
  "ds_read_b128 v[100:103], %[xa] offset:240\n\t"

#define VCLOB \
  "v40","v41","v42","v43","v44","v45","v46","v47","v48","v49", \
  "v50","v51","v52","v53","v54","v55","v56","v57","v58","v59", \
  "v60","v61","v62","v63","v64","v65","v66","v67","v68","v69", \
  "v70","v71","v72","v73","v74","v75","v76","v77","v78","v79", \
  "v80","v81","v82","v83","v84","v85","v86","v87","v88","v89", \
  "v90","v91","v92","v93","v94","v95","v96","v97","v98","v99", \
  "v100","v101","v102","v103","v104"

#define SCLOB \
  "s36","s37","s38","s39","s40","s41","s42","s43","s44","s45", \
  "s46","s47","s48","s49","s50","s51","s52","s53","s54","s55", \
  "s56","s57","s58","s59","s60","s61","s62","s63","s64","s65", \
  "s66","s67","s68","s69","s70","s71","s72","s73","s74","s75", \
  "s76","s77","s78","s79","s80","s81","s82","s83","s84","s85", \
  "s86","s87","s88","s89","s90","s91","s92","s93","s94","s95", \
  "s96","s97","s98","s99"

// one slab: 16 outputs (rows TP..TP+15 of T, row stride 256B)
#define DCT16(AA, TPX) \
  asm volatile( \
    XLOAD \
    ROWM("%[a0]",  "0","64","128","192") \
    ROWM("%[a1]",  "256","320","384","448") \
    ROWM("%[a2]",  "512","576","640","704") \
    ROWM("%[a3]",  "768","832","896","960") \
    ROWM("%[a4]",  "1024","1088","1152","1216") \
    ROWM("%[a5]",  "1280","1344","1408","1472") \
    ROWM("%[a6]",  "1536","1600","1664","1728") \
    ROWM("%[a7]",  "1792","1856","1920","1984") \
    ROWM("%[a8]",  "2048","2112","2176","2240") \
    ROWM("%[a9]",  "2304","2368","2432","2496") \
    ROWM("%[a10]", "2560","2624","2688","2752") \
    ROWM("%[a11]", "2816","2880","2944","3008") \
    ROWM("%[a12]", "3072","3136","3200","3264") \
    ROWM("%[a13]", "3328","3392","3456","3520") \
    ROWM("%[a14]", "3584","3648","3712","3776") \
    ROWM("%[a15]", "3840","3904","3968","4032") \
    : [a0]"=&v"(AA##0),  [a1]"=&v"(AA##1),  [a2]"=&v"(AA##2),  [a3]"=&v"(AA##3), \
      [a4]"=&v"(AA##4),  [a5]"=&v"(AA##5),  [a6]"=&v"(AA##6),  [a7]"=&v"(AA##7), \
      [a8]"=&v"(AA##8),  [a9]"=&v"(AA##9),  [a10]"=&v"(AA##10),[a11]"=&v"(AA##11), \
      [a12]"=&v"(AA##12),[a13]"=&v"(AA##13),[a14]"=&v"(AA##14),[a15]"=&v"(AA##15) \
    : [xa]"v"(xaddr), [tp]"s"(TPX) \
    : "memory", VCLOB, SCLOB)

// grid: 2048 wg x 256 thr. wg = 64x64-px region: 64 Y + 16 Cb + 16 Cr blocks.
// Phase 2: wave0/1 -> Y blocks (lane=block), i in [0,32)/[32,64);
//          wave2/3 -> chroma blocks 64+(lane&31) (lanes 0-31), same i split.
__global__ __launch_bounds__(256, 4)
void jpeg_kernel(const float* __restrict__ img, float* __restrict__ out) {
  __shared__ float LDSbuf[96 * 68];  // X region; slab overlays AFTER barrier 2

  const int t = threadIdx.x;
  const int lane = t & 63;
  const int w = __builtin_amdgcn_readfirstlane(t >> 6);  // uniform wave id
  const int wid = blockIdx.x;
  const int b = wid >> 6;   // batch 0..31
  const int r = wid & 63;   // region 0..63

  // ================= phase 1: merged staging (r8/r13 verbatim) ==============
  {
    const int yb = t & 63;
    const int q = t >> 6;
    const int by = yb >> 3, bx = yb & 7;
    const int prow = (r >> 3) * 64 + by * 8 + 2 * q;
    const int pcol = (r & 7) * 64 + bx * 8;
    const float* rp = img + (size_t)b * 786432 + (size_t)prow * 512 + pcol;

    float tv[3][2][8];
#pragma unroll
    for (int c = 0; c < 3; ++c) {
#pragma unroll
      for (int rr = 0; rr < 2; ++rr) {
        const float* p0 = rp + c * 262144 + rr * 512;
        const float4 va = *(const float4*)(p0);
        const float4 vb = *(const float4*)(p0 + 4);
        tv[c][rr][0] = vmul(va.x, 255.0f);
        tv[c][rr][1] = vmul(va.y, 255.0f);
        tv[c][rr][2] = vmul(va.z, 255.0f);
        tv[c][rr][3] = vmul(va.w, 255.0f);
        tv[c][rr][4] = vmul(vb.x, 255.0f);
        tv[c][rr][5] = vmul(vb.y, 255.0f);
        tv[c][rr][6] = vmul(vb.z, 255.0f);
        tv[c][rr][7] = vmul(vb.w, 255.0f);
      }
    }
#pragma unroll
    for (int rr = 0; rr < 2; ++rr) {
#pragma unroll
      for (int y = 0; y < 8; ++y) {
        float a = vmul(tv[0][rr][y], 0.299f);
        a = vadd(a, vmul(tv[1][rr][y], 0.587f));
        a = vadd(a, vmul(tv[2][rr][y], 0.114f));
        LDSbuf[yb * 68 + 16 * q + rr * 8 + y] = vsubf(a, 128.0f);
      }
    }
    const int lcr = 4 * by + q;
#pragma unroll
    for (int pc = 0; pc < 4; ++pc) {
      const int lcc = 4 * bx + pc;
      const int crow = 64 + ((lcr >> 3) * 4 + (lcc >> 3));
      const int cell = (lcr & 7) * 8 + (lcc & 7);
      const int e = 2 * pc, o = 2 * pc + 1;
      {
        const float p00 = chro_t(tv[0][0][e], tv[1][0][e], tv[2][0][e], -0.168736f, -0.331264f, 0.5f);
        const float p01 = chro_t(tv[0][0][o], tv[1][0][o], tv[2][0][o], -0.168736f, -0.331264f, 0.5f);
        const float p10 = chro_t(tv[0][1][e], tv[1][1][e], tv[2][1][e], -0.168736f, -0.331264f, 0.5f);
        const float p11 = chro_t(tv[0][1][o], tv[1][1][o], tv[2][1][o], -0.168736f, -0.331264f, 0.5f);
        const float s = vadd(vadd(vadd(p00, p01), p10), p11);
        LDSbuf[crow * 68 + cell] = vsubf(vmul(s, 0.25f), 128.0f);
      }
      {
        const float p00 = chro_t(tv[0][0][e], tv[1][0][e], tv[2][0][e], 0.5f, -0.418688f, -0.081312f);
        const float p01 = chro_t(tv[0][0][o], tv[1][0][o], tv[2][0][o], 0.5f, -0.418688f, -0.081312f);
        const float p10 = chro_t(tv[0][1][e], tv[1][1][e], tv[2][1][e], 0.5f, -0.418688f, -0.081312f);
        const float p11 = chro_t(tv[0][1][o], tv[1][1][o], tv[2][1][o], 0.5f, -0.418688f, -0.081312f);
        const float s = vadd(vadd(vadd(p00, p01), p10), p11);
        LDSbuf[(crow + 16) * 68 + cell] = vsubf(vmul(s, 0.25f), 128.0f);
      }
    }
  }

  // ================= phase 2: mega-asm DCT =================
  const int ibase = (w & 1) * 32;
  const bool chro = (w >= 2);
  const bool active = (!chro) || (lane < 32);
  const int blk = chro ? (64 + (lane & 31)) : lane;
  const float* qt = chro ? TT.cq : TT.yq;  // uniform (constant AS)

  // LDS byte offset of this lane's 64-float X row (addrspace(3) value = offset)
  const unsigned xaddr = (unsigned)(size_t)(&LDSbuf[blk * 68]);
  const float* tp0 = TT.tr + (size_t)(ibase) * 64;        // slab f=0 rows
  const float* tp1 = TT.tr + (size_t)(ibase + 16) * 64;   // slab f=1 rows

  float aa0, aa1, aa2, aa3, aa4, aa5, aa6, aa7;
  float aa8, aa9, aa10, aa11, aa12, aa13, aa14, aa15;
  float bb0, bb1, bb2, bb3, bb4, bb5, bb6, bb7;
  float bb8, bb9, bb10, bb11, bb12, bb13, bb14, bb15;

  __syncthreads();  // staging complete

  if (active) {
    DCT16(aa, tp0);
    DCT16(bb, tp1);
  }

  __syncthreads();  // all X reads done; LDSbuf reusable as transpose slab

  const int ybase = b * 4096 + (r >> 3) * 512 + (r & 7) * 8;
  const int cbase = b * 1024 + (r >> 3) * 128 + (r & 7) * 4;

#define QSTORE(A, B, C, D, G, CO) do { \
    float4 v4_; \
    v4_.x = q4(A, TT.sc[(CO) + 4*(G) + 0], qt[(CO) + 4*(G) + 0]); \
    v4_.y = q4(B, TT.sc[(CO) + 4*(G) + 1], qt[(CO) + 4*(G) + 1]); \
    v4_.z = q4(C, TT.sc[(CO) + 4*(G) + 2], qt[(CO) + 4*(G) + 2]); \
    v4_.w = q4(D, TT.sc[(CO) + 4*(G) + 3], qt[(CO) + 4*(G) + 3]); \
    *(float4*)&LDSbuf[(w * 64 + lane) * 20 + 4*(G)] = v4_; \
  } while (0)

  // ---- slab f=0 (coeffs ibase .. ibase+15) ----
  {
    const int co = ibase;
    if (active) {
      QSTORE(aa0,  aa1,  aa2,  aa3,  0, co);
      QSTORE(aa4,  aa5,  aa6,  aa7,  1, co);
      QSTORE(aa8,  aa9,  aa10, aa11, 2, co);
      QSTORE(aa12, aa13, aa14, aa15, 3, co);
    }
    if (!chro) {
#pragma unroll
      for (int k = 0; k < 4; ++k) {
        const int B = k * 16 + (lane >> 2);
        const int e0 = (lane & 3) * 4;
        const float4 vv = *(const float4*)&LDSbuf[(w * 64 + B) * 20 + e0];
        const unsigned ob = (unsigned)(ybase + (B >> 3) * 64 + (B & 7));
        *(float4*)&out[(ob << 6) + (unsigned)(co + e0)] = vv;
      }
    } else {
#pragma unroll
      for (int k = 0; k < 2; ++k) {
        const int idx = k * 64 + lane;
        const int B = idx >> 2;
        const int e0 = (idx & 3) * 4;
        const float4 vv = *(const float4*)&LDSbuf[(w * 64 + B) * 20 + e0];
        const int cc = B & 15;
        const unsigned ob = 8388608u + (B >= 16 ? 2097152u : 0u) +
            (((unsigned)(cbase + (cc >> 2) * 32 + (cc & 3))) << 6);
        *(float4*)&out[ob + (unsigned)(co + e0)] = vv;
      }
    }
  }

  // ---- slab f=1 (coeffs ibase+16 .. ibase+31) ----
  {
    const int co = ibase + 16;
    if (active) {
      QSTORE(bb0,  bb1,  bb2,  bb3,  0, co);
      QSTORE(bb4,  bb5,  bb6,  bb7,  1, co);
      QSTORE(bb8,  bb9,  bb10, bb11, 2, co);
      QSTORE(bb12, bb13, bb14, bb15, 3, co);
    }
    if (!chro) {
#pragma unroll
      for (int k = 0; k < 4; ++k) {
        const int B = k * 16 + (lane >> 2);
        const int e0 = (lane & 3) * 4;
        const float4 vv = *(const float4*)&LDSbuf[(w * 64 + B) * 20 + e0];
        const unsigned ob = (unsigned)(ybase + (B >> 3) * 64 + (B & 7));
        *(float4*)&out[(ob << 6) + (unsigned)(co + e0)] = vv;
      }
    } else {
#pragma unroll
      for (int k = 0; k < 2; ++k) {
        const int idx = k * 64 + lane;
        const int B = idx >> 2;
        const int e0 = (idx & 3) * 4;
        const float4 vv = *(const float4*)&LDSbuf[(w * 64 + B) * 20 + e0];
        const int cc = B & 15;
        const unsigned ob = 8388608u + (B >= 16 ? 2097152u : 0u) +
            (((unsigned)(cbase + (cc >> 2) * 32 + (cc & 3))) << 6);
        *(float4*)&out[ob + (unsigned)(co + e0)] = vv;
      }
    }
  }
#undef QSTORE
}

extern "C" void kernel_launch(void* const* d_in, const int* in_sizes, int n_in,
                              void* d_out, int out_size, void* d_ws, size_t ws_size,
                              hipStream_t stream) {
  (void)in_sizes; (void)n_in; (void)d_ws; (void)ws_size; (void)out_size;
  const float* img = (const float*)d_in[0];
  float* out = (float*)d_out;
  jpeg_kernel<<<dim3(2048), dim3(256), 0, stream>>>(img, out);
}